// Round 17
// baseline (1636.591 us; speedup 1.0000x reference)
//
#include <hip/hip_runtime.h>
#include <stdint.h>

#define HH 224
#define WW 224
#define NSEAM 7
#define BWIDTH 5
#define BB 256
#define KK 64
#define YCH 8
#define YROWS (HH / YCH)

#define REP_FULL 8
#define REP_MEM  24
#define REP_CMP  48
#define REP_T0   8

// DPP helpers (ctrl must be literal): row_shr:1=0x111 (dst[i]=src[i-1]),
// row_shl:1=0x101 (dst[i]=src[i+1]), row_ror:N=0x120+N. Rows = 16 lanes.
#define DPPF_OLD(old, src, ctrl) \
    __int_as_float(__builtin_amdgcn_update_dpp(__float_as_int(old), __float_as_int(src), ctrl, 0xF, 0xF, false))
#define DPPF_Z(src, ctrl) \
    __int_as_float(__builtin_amdgcn_update_dpp(0, __float_as_int(src), ctrl, 0xF, 0xF, true))
#define DPPI_Z(src, ctrl) \
    __builtin_amdgcn_update_dpp(0, (int)(src), ctrl, 0xF, 0xF, true)

// Shared DP row step: candidates [jm, j, jp], strict-< first-min, ballot
// choice pack. Requires locals: cost, j, sel0, shb, grp, ch.
#define ROWSTEP(BUF, rr, rbase)                                             \
    {                                                                       \
        float pm  = DPPF_OLD(cost, cost, 0x111);                            \
        float ppv = DPPF_OLD(cost, cost, 0x101);                            \
        ppv = (j >= 10) ? cost : ppv;                                       \
        float best = fminf(fminf(pm, cost), ppv);                           \
        int sel = (pm == best) ? sel0 : ((cost == best) ? 1 : 2);           \
        cost = best - BUF[rr];                                              \
        unsigned long long b0 = __ballot(sel & 1);                          \
        unsigned long long b1 = __ballot(sel & 2);                          \
        if (j == 0) ch[grp][(rbase) + rr] =                                 \
            (uint32_t)(((b0 >> shb) & 0xFFFFull) |                          \
                       (((b1 >> shb) & 0xFFFFull) << 16));                  \
    }

#define PROCC(BUF, cbase)                                                   \
    _Pragma("unroll")                                                       \
    for (int rr = 0; rr < 16; ++rr) ROWSTEP(BUF, rr, (cbase) * 16)

#define LOADC(BUF, c, OFF)                                                  \
    if (dir == 0) {                                                         \
        _Pragma("unroll")                                                   \
        for (int rr = 0; rr < 16; ++rr) BUF[rr] = gp0[((c) * 16 + rr) * WW + (OFF)];\
    } else {                                                                \
        const float4* q4 = reinterpret_cast<const float4*>(gp1 + (c) * 16 + (OFF));\
        float4 t0 = q4[0], t1 = q4[1], t2 = q4[2], t3 = q4[3];              \
        BUF[0] = t0.x;  BUF[1] = t0.y;  BUF[2] = t0.z;  BUF[3] = t0.w;      \
        BUF[4] = t1.x;  BUF[5] = t1.y;  BUF[6] = t1.z;  BUF[7] = t1.w;      \
        BUF[8] = t2.x;  BUF[9] = t2.y;  BUF[10] = t2.z; BUF[11] = t2.w;     \
        BUF[12] = t3.x; BUF[13] = t3.y; BUF[14] = t3.z; BUF[15] = t3.w;     \
    }

// FIXED vs R16: store uses the [b][dir*7+p] layout that label_kernel reads
// (R16's macro wrote gid-major = dir-major and broke the real pipeline).
#define ARGMIN_BACKTRACK_STORE                                              \
    {                                                                       \
        float rc = (j <= 10) ? cost : INFINITY;                             \
        int   ri = (j <= 10) ? j : 15;                                      \
        {float oc=DPPF_Z(rc,0x128); int oi=DPPI_Z(ri,0x128);                \
         bool t=(oc<rc)||(oc==rc&&oi<ri); rc=t?oc:rc; ri=t?oi:ri;}          \
        {float oc=DPPF_Z(rc,0x124); int oi=DPPI_Z(ri,0x124);                \
         bool t=(oc<rc)||(oc==rc&&oi<ri); rc=t?oc:rc; ri=t?oi:ri;}          \
        {float oc=DPPF_Z(rc,0x122); int oi=DPPI_Z(ri,0x122);                \
         bool t=(oc<rc)||(oc==rc&&oi<ri); rc=t?oc:rc; ri=t?oi:ri;}          \
        {float oc=DPPF_Z(rc,0x121); int oi=DPPI_Z(ri,0x121);                \
         bool t=(oc<rc)||(oc==rc&&oi<ri); rc=t?oc:rc; ri=t?oi:ri;}          \
        int pos = ri;                                                       \
        if (j == 0) pth[grp][HH - 1] = band0 + pos;                         \
        _Pragma("unroll 1")                                                 \
        for (int c = 13; c >= 0; --c) {                                     \
            uint32_t w[16];                                                 \
            _Pragma("unroll")                                               \
            for (int rr = 0; rr < 16; ++rr) w[rr] = ch[grp][c * 16 + rr];   \
            _Pragma("unroll")                                               \
            for (int rr = 15; rr >= 0; --rr) {                              \
                int r = c * 16 + rr;                                        \
                if (r >= 1) {                                               \
                    uint32_t ww = w[rr];                                    \
                    int sel = (int)((ww >> pos) & 1u) | (int)((ww >> (pos + 15)) & 2u);\
                    pos += sel - 1;                                         \
                    if (j == 0) pth[grp][r - 1] = band0 + pos;              \
                }                                                           \
            }                                                               \
        }                                                                   \
        int* op = paths + (size_t)(b * 14 + dir * NSEAM + p) * HH;          \
        _Pragma("unroll 1")                                                 \
        for (int c = 0; c < 14; ++c) op[c * 16 + j] = pth[grp][c * 16 + j]; \
    }

#define DP_PREAMBLE                                                         \
    const int j   = threadIdx.x & 15;                                       \
    const int grp = threadIdx.x >> 4;                                       \
    const int gid = blockIdx.x * 16 + grp;                                  \
    const int dir = gid / (BB * NSEAM);                                     \
    const int rem = gid - dir * (BB * NSEAM);                               \
    const int b   = rem / NSEAM;                                            \
    const int p   = rem - b * NSEAM;                                        \
    const int band0 = 28 * (p + 1) - BWIDTH;                                \
    const int jc  = (j > 10) ? 10 : j;                                      \
    const float* gb  = g + (size_t)b * HH * WW;                             \
    const float* gp0 = gb + band0 + jc;                                     \
    const float* gp1 = gb + (size_t)(band0 + jc) * WW;                      \
    const int shb  = threadIdx.x & 48;                                      \
    const int sel0 = (j == 0) ? 1 : 0;

// ---------------------------------------------------------------------------
// PROBE 1: full dp, REP_FULL reps. 8 * t_dp.
// ---------------------------------------------------------------------------
__global__ __launch_bounds__(256) void probe_full(const float* __restrict__ g,
                                                  int* __restrict__ paths) {
    __shared__ uint32_t ch[16][226];
    __shared__ int      pth[16][226];
    DP_PREAMBLE
    float bufA[16], bufB[16], cost;
#pragma unroll 1
    for (int rep = 0; rep < REP_FULL; ++rep) {
        int off = 0;
        asm volatile("" : "+v"(off));          // opaque 0: defeats LICM
        LOADC(bufA, 0, off);
        LOADC(bufB, 1, off);
        cost = -bufA[0];
#pragma unroll
        for (int rr = 1; rr < 16; ++rr) ROWSTEP(bufA, rr, 0);
        LOADC(bufA, 2, off);
        PROCC(bufB, 1);
        LOADC(bufB, 3, off);
#pragma unroll 1
        for (int c2 = 2; c2 <= 12; c2 += 2) {
            PROCC(bufA, c2);
            if (c2 + 2 < 14) LOADC(bufA, c2 + 2, off);
            PROCC(bufB, c2 + 1);
            if (c2 + 3 < 14) LOADC(bufB, c2 + 3, off);
        }
        ARGMIN_BACKTRACK_STORE
    }
}

// ---------------------------------------------------------------------------
// PROBE 2: loads only (identical issue structure), values consumed by asm.
// 24 * t_mem.
// ---------------------------------------------------------------------------
__global__ __launch_bounds__(256) void probe_mem(const float* __restrict__ g,
                                                 int* __restrict__ paths) {
    DP_PREAMBLE
    (void)band0; (void)p; (void)b;
    float bufA[16], bufB[16];
#define CONSUME(BUF)                                                        \
    _Pragma("unroll")                                                       \
    for (int rr = 0; rr < 16; ++rr) asm volatile("" :: "v"(BUF[rr]));
#pragma unroll 1
    for (int rep = 0; rep < REP_MEM; ++rep) {
        int off = 0;
        asm volatile("" : "+v"(off));
        LOADC(bufA, 0, off);
        LOADC(bufB, 1, off);
        CONSUME(bufA)
        LOADC(bufA, 2, off);
        CONSUME(bufB)
        LOADC(bufB, 3, off);
#pragma unroll 1
        for (int c2 = 2; c2 <= 12; c2 += 2) {
            CONSUME(bufA)
            if (c2 + 2 < 14) LOADC(bufA, c2 + 2, off);
            CONSUME(bufB)
            if (c2 + 3 < 14) LOADC(bufB, c2 + 3, off);
        }
    }
#undef CONSUME
}

// ---------------------------------------------------------------------------
// PROBE 3: compute chain only — buffers loaded once, DP+ballot+backtrack
// runs REP_CMP times from registers. 48 * t_compute.
// ---------------------------------------------------------------------------
__global__ __launch_bounds__(256) void probe_cmp(const float* __restrict__ g,
                                                 int* __restrict__ paths) {
    __shared__ uint32_t ch[16][226];
    __shared__ int      pth[16][226];
    DP_PREAMBLE
    float bufA[16], bufB[16], bufC[16], bufD[16], cost;
    {
        int off = 0;
        asm volatile("" : "+v"(off));
        LOADC(bufA, 0, off);
        LOADC(bufB, 1, off);
        LOADC(bufC, 2, off);
        LOADC(bufD, 3, off);
    }
#pragma unroll 1
    for (int rep = 0; rep < REP_CMP; ++rep) {
        float ci = -bufA[0];
        asm volatile("" : "+v"(ci));           // rep-dependent: defeats LICM
        cost = ci;
#pragma unroll
        for (int rr = 1; rr < 16; ++rr) ROWSTEP(bufA, rr, 0);
        PROCC(bufB, 1);
#pragma unroll 1
        for (int c2 = 2; c2 <= 12; c2 += 2) {
            PROCC(bufC, c2);
            PROCC(bufD, c2 + 1);
        }
        PROCC(bufB, 13);
        ARGMIN_BACKTRACK_STORE
    }
}

// ---------------------------------------------------------------------------
// PROBE 4: full dp with dir0 loads as per-lane float4 ROW loads + wave-local
// LDS transpose (16x17 tile per group, wave-lockstep so no barriers) ->
// dir0 fetches 1 fully-used 64B line per lane per chunk. dir1 unchanged.
// Window clamped in-image (reads shifted, probe-only). 8 * t_dp_t0.
// ---------------------------------------------------------------------------
__global__ __launch_bounds__(256) void probe_t0(const float* __restrict__ g,
                                                int* __restrict__ paths) {
    __shared__ uint32_t ch[16][226];
    __shared__ int      pth[16][226];
    __shared__ float    tileT[16][16 * 17];
    DP_PREAMBLE
    const int colA = (band0 + 16 <= WW) ? (band0 & ~3) : (WW - 16);  // in-image
    const int cofs = band0 - colA;
    const float* gq0 = gb + colA;

#define LOADR0(SET, c, OFF)                                                 \
    {                                                                       \
        const float4* r4 = reinterpret_cast<const float4*>(                 \
            gq0 + (size_t)((c) * 16 + j) * WW + (OFF));                     \
        float4 t0 = r4[0], t1 = r4[1], t2 = r4[2], t3 = r4[3];              \
        SET[0]=t0.x;  SET[1]=t0.y;  SET[2]=t0.z;  SET[3]=t0.w;              \
        SET[4]=t1.x;  SET[5]=t1.y;  SET[6]=t1.z;  SET[7]=t1.w;              \
        SET[8]=t2.x;  SET[9]=t2.y;  SET[10]=t2.z; SET[11]=t2.w;             \
        SET[12]=t3.x; SET[13]=t3.y; SET[14]=t3.z; SET[15]=t3.w;             \
    }
#define TRN(SET, TB)                                                        \
    {                                                                       \
        _Pragma("unroll")                                                   \
        for (int k = 0; k < 16; ++k) tileT[grp][j * 17 + k] = SET[k];       \
        _Pragma("unroll")                                                   \
        for (int rr = 0; rr < 16; ++rr) TB[rr] = tileT[grp][rr * 17 + cofs + jc];\
    }

    if (dir == 0) {
        float rA[16], rB[16], tb[16], cost;
#pragma unroll 1
        for (int rep = 0; rep < REP_T0; ++rep) {
            int off = 0;
            asm volatile("" : "+v"(off));
            LOADR0(rA, 0, off);
            LOADR0(rB, 1, off);
            TRN(rA, tb)
            LOADR0(rA, 2, off);
            cost = -tb[0];
#pragma unroll
            for (int rr = 1; rr < 16; ++rr) ROWSTEP(tb, rr, 0);
#pragma unroll 1
            for (int c2 = 1; c2 <= 13; c2 += 2) {
                TRN(rB, tb)
                if (c2 + 2 < 14) LOADR0(rB, c2 + 2, off);
                PROCC(tb, c2);
                if (c2 + 1 < 14) {
                    TRN(rA, tb)
                    if (c2 + 3 < 14) LOADR0(rA, c2 + 3, off);
                    PROCC(tb, c2 + 1);
                }
            }
            ARGMIN_BACKTRACK_STORE
        }
    } else {
        float bufA[16], bufB[16], cost;
#pragma unroll 1
        for (int rep = 0; rep < REP_T0; ++rep) {
            int off = 0;
            asm volatile("" : "+v"(off));
            LOADC(bufA, 0, off);
            LOADC(bufB, 1, off);
            cost = -bufA[0];
#pragma unroll
            for (int rr = 1; rr < 16; ++rr) ROWSTEP(bufA, rr, 0);
            LOADC(bufA, 2, off);
            PROCC(bufB, 1);
            LOADC(bufB, 3, off);
#pragma unroll 1
            for (int c2 = 2; c2 <= 12; c2 += 2) {
                PROCC(bufA, c2);
                if (c2 + 2 < 14) LOADC(bufA, c2 + 2, off);
                PROCC(bufB, c2 + 1);
                if (c2 + 3 < 14) LOADC(bufB, c2 + 3, off);
            }
            ARGMIN_BACKTRACK_STORE
        }
    }
#undef LOADR0
#undef TRN
}

// ---------------------------------------------------------------------------
// REAL kernel 1: seam DP (R15, depth-4). Zeroes gacc. Store layout fixed.
// ---------------------------------------------------------------------------
__global__ __launch_bounds__(256) void dp_kernel(const float* __restrict__ g,
                                                 int* __restrict__ paths,
                                                 unsigned long long* __restrict__ gacc) {
    __shared__ uint32_t ch[16][226];
    __shared__ int      pth[16][226];
    {
        int t = blockIdx.x * 256 + threadIdx.x;
        if (t < BB * KK) gacc[t] = 0ull;
    }
    DP_PREAMBLE
    float bufA[16], bufB[16], bufC[16], bufD[16], cost;
    LOADC(bufA, 0, 0);
    LOADC(bufB, 1, 0);
    LOADC(bufC, 2, 0);
    LOADC(bufD, 3, 0);
    cost = -bufA[0];
#pragma unroll
    for (int rr = 1; rr < 16; ++rr) ROWSTEP(bufA, rr, 0);
    LOADC(bufA, 4, 0);
#pragma unroll 1
    for (int c = 1; c <= 9; c += 4) {
        PROCC(bufB, c);
        if (c + 4 < 14) LOADC(bufB, c + 4, 0);
        PROCC(bufC, c + 1);
        if (c + 5 < 14) LOADC(bufC, c + 5, 0);
        PROCC(bufD, c + 2);
        if (c + 6 < 14) LOADC(bufD, c + 6, 0);
        PROCC(bufA, c + 3);
        if (c + 7 < 14) LOADC(bufA, c + 7, 0);
    }
    PROCC(bufB, 13);
    ARGMIN_BACKTRACK_STORE
}

// ---------------------------------------------------------------------------
// REAL kernel 2: labels + centroid partials (R13-proven, unchanged).
// ---------------------------------------------------------------------------
__global__ __launch_bounds__(256) void label_kernel(const int* __restrict__ paths,
                                                    float* __restrict__ out,
                                                    unsigned long long* __restrict__ gacc) {
    const int b  = blockIdx.x >> 3;
    const int cy = blockIdx.x & 7;
    const int y0 = cy * YROWS;

    __shared__ unsigned char vpc[NSEAM][YROWS];
    __shared__ unsigned long long acc[KK];

    const int* pb = paths + (size_t)b * 14 * HH;
    for (int i = threadIdx.x; i < NSEAM * YROWS; i += 256) {
        int q = i / YROWS, r = i - q * YROWS;
        vpc[q][r] = (unsigned char)pb[q * HH + y0 + r];
    }
    if (threadIdx.x < KK) acc[threadIdx.x] = 0ull;
    __syncthreads();

    const int x = threadIdx.x;
    if (x < WW) {
        int basev = 0, kv = 0, inv = 0;
        if (x >= 23) {
            int q = x - 23, k = q / 28, r = q - k * 28;
            if (k > 6) basev = 7;
            else { inv = (r <= 10) ? 1 : 0; basev = k + (r > 10 ? 1 : 0); kv = k; }
        }
        const int hA = (cy >= 1) ? pb[(NSEAM + cy - 1) * HH + x] : 0;
        const int hB = (cy <= 6) ? pb[(NSEAM + cy) * HH + x] : 0;

        float* mb = out + (size_t)BB * KK * 2 + (size_t)b * HH * WW + x;
        int cur = -1, ys = y0;

#define FLUSH(yend)                                                          \
        {                                                                    \
            unsigned cnt = (unsigned)((yend) - ys);                          \
            unsigned sy  = (unsigned)((ys + (yend) - 1) * ((yend) - ys) / 2);\
            unsigned sx  = (unsigned)x * cnt;                                \
            atomicAdd(&acc[cur], ((unsigned long long)cnt << 42) |           \
                                 ((unsigned long long)sy << 21) |            \
                                 (unsigned long long)sx);                    \
        }
#define ROW(t, HLEXPR)                                                       \
        {                                                                    \
            const int y = y0 + (t);                                          \
            int vl = basev + ((inv && (int)vpc[kv][t] <= x) ? 1 : 0);        \
            int lab = vl + 8 * (HLEXPR);                                     \
            mb[y * WW] = (float)lab;                                         \
            if (lab != cur) { if (cur >= 0) FLUSH(y); cur = lab; ys = y; }   \
        }
#pragma unroll
        for (int t = 0; t < 6; ++t)
            ROW(t, (cy >= 1) ? (cy - 1 + ((hA <= y0 + t) ? 1 : 0)) : 0)
#pragma unroll
        for (int t = 6; t < 23; ++t)
            ROW(t, cy)
#pragma unroll
        for (int t = 23; t < 28; ++t)
            ROW(t, (cy <= 6) ? (cy + ((hB <= y0 + t) ? 1 : 0)) : 7)
        FLUSH(y0 + YROWS)
#undef ROW
#undef FLUSH
    }
    __syncthreads();

    if (threadIdx.x < KK) {
        unsigned long long v = acc[threadIdx.x];
        if (v) atomicAdd(&gacc[(size_t)b * KK + threadIdx.x], v);
    }
}

// ---------------------------------------------------------------------------
// REAL kernel 3: finalize centroids.
// ---------------------------------------------------------------------------
__global__ __launch_bounds__(256) void finalize_kernel(const unsigned long long* __restrict__ gacc,
                                                       float* __restrict__ out) {
    int i = blockIdx.x * 256 + threadIdx.x;
    unsigned long long sv = gacc[i];
    float cnt = (float)(unsigned)(sv >> 42);
    float sy  = (float)(unsigned)((sv >> 21) & 0x1FFFFFu);
    float sx  = (float)(unsigned)(sv & 0x1FFFFFu);
    float c = fmaxf(cnt, 1e-6f);
    float2 r; r.x = sy / c; r.y = sx / c;
    *reinterpret_cast<float2*>(out + (size_t)i * 2) = r;
}

extern "C" void kernel_launch(void* const* d_in, const int* in_sizes, int n_in,
                              void* d_out, int out_size, void* d_ws, size_t ws_size,
                              hipStream_t stream) {
    const float* g = (const float*)d_in[1];
    float* out = (float*)d_out;
    int* paths = (int*)d_ws;                                        // 3,211,264 B
    unsigned long long* gacc =
        (unsigned long long*)((char*)d_ws + (size_t)BB * 14 * HH * 4);   // 128 KiB

    // probes (write only paths scratch; real dp fully overwrites it after)
    probe_full<<<(BB * 14) / 16, 256, 0, stream>>>(g, paths);
    probe_mem <<<(BB * 14) / 16, 256, 0, stream>>>(g, paths);
    probe_cmp <<<(BB * 14) / 16, 256, 0, stream>>>(g, paths);
    probe_t0  <<<(BB * 14) / 16, 256, 0, stream>>>(g, paths);

    // real pipeline (R15 state, store layout fixed)
    dp_kernel<<<(BB * 14) / 16, 256, 0, stream>>>(g, paths, gacc);
    label_kernel<<<BB * YCH, 256, 0, stream>>>(paths, out, gacc);
    finalize_kernel<<<(BB * KK) / 256, 256, 0, stream>>>(gacc, out);
}

// Round 18
// 68.059 us; speedup vs baseline: 24.0466x; 24.0466x over previous
//
#include <hip/hip_runtime.h>
#include <stdint.h>

#define HH 224
#define WW 224
#define NSEAM 7
#define BWIDTH 5
#define BB 256
#define KK 64
#define YCH 8
#define YROWS (HH / YCH)

// DPP helpers (ctrl must be literal): row_shr:1=0x111 (dst[i]=src[i-1]),
// row_shl:1=0x101 (dst[i]=src[i+1]), row_ror:N=0x120+N. Rows = 16 lanes.
#define DPPF_OLD(old, src, ctrl) \
    __int_as_float(__builtin_amdgcn_update_dpp(__float_as_int(old), __float_as_int(src), ctrl, 0xF, 0xF, false))
#define DPPF_Z(src, ctrl) \
    __int_as_float(__builtin_amdgcn_update_dpp(0, __float_as_int(src), ctrl, 0xF, 0xF, true))
#define DPPI_Z(src, ctrl) \
    __builtin_amdgcn_update_dpp(0, (int)(src), ctrl, 0xF, 0xF, true)

// ---------------------------------------------------------------------------
// Kernel 1: seam DP, TWO DPs per 16-lane group (dir0 + dir1 of same (b,p)),
// row-interleaved. R17 probes: compute chain = 21.9us of dp's ~23 (87%
// per-wave stall, VALUBusy 45% at 0.85 waves/SIMD) -> loads irrelevant,
// latency-stall-bound. Interleaving two independent chains per thread issues
// B's ops in A's stall shadow. Grid = 112 blocks. DP math byte-identical to
// the absmax-0-proven formula; stores in [b][dir*7+p] layout. Zeroes gacc.
// ---------------------------------------------------------------------------
__global__ __launch_bounds__(256) void dp_kernel(const float* __restrict__ g,
                                                 int* __restrict__ paths,
                                                 unsigned long long* __restrict__ gacc) {
    __shared__ uint32_t chA[16][226], chB[16][226];  // per-row packed sels
    __shared__ int      pthA[16][226], pthB[16][226];

    {   // zero global centroid accumulators (28,672 threads >= 16,384)
        int t = blockIdx.x * 256 + threadIdx.x;
        if (t < BB * KK) gacc[t] = 0ull;
    }

    const int j   = threadIdx.x & 15;
    const int grp = threadIdx.x >> 4;
    const int pi  = blockIdx.x * 16 + grp;      // 0..1791 = b*7+p
    const int b   = pi / NSEAM;
    const int p   = pi - b * NSEAM;
    const int band0 = 28 * (p + 1) - BWIDTH;
    const int jc  = (j > 10) ? 10 : j;
    const float* gb  = g + (size_t)b * HH * WW;
    const float* gp0 = gb + band0 + jc;                 // dir0: strided rows
    const float* gp1 = gb + (size_t)(band0 + jc) * WW;  // dir1: contiguous cols
    const int shb  = threadIdx.x & 48;
    const int sel0 = (j == 0) ? 1 : 0;

    float a0[16], a1[16], b0_[16], b1_[16];
    float cost_a, cost_b;

#define LOAD0(BUF, c)                                                       \
    _Pragma("unroll")                                                       \
    for (int rr = 0; rr < 16; ++rr) BUF[rr] = gp0[((c) * 16 + rr) * WW];

#define LOAD1(BUF, c)                                                       \
    {                                                                       \
        const float4* q4 = reinterpret_cast<const float4*>(gp1 + (c) * 16); \
        float4 t0 = q4[0], t1 = q4[1], t2 = q4[2], t3 = q4[3];              \
        BUF[0] = t0.x;  BUF[1] = t0.y;  BUF[2] = t0.z;  BUF[3] = t0.w;      \
        BUF[4] = t1.x;  BUF[5] = t1.y;  BUF[6] = t1.z;  BUF[7] = t1.w;      \
        BUF[8] = t2.x;  BUF[9] = t2.y;  BUF[10] = t2.z; BUF[11] = t2.w;     \
        BUF[12] = t3.x; BUF[13] = t3.y; BUF[14] = t3.z; BUF[15] = t3.w;     \
    }

// one DP row step for chain (COST, CH): candidates [jm,j,jp], strict-<
// first-min, ballot pack -- byte-identical math to R11-R15 (absmax 0).
#define RS(BUF, rr, rbase, COST, CH)                                        \
    {                                                                       \
        float pm  = DPPF_OLD(COST, COST, 0x111);                            \
        float ppv = DPPF_OLD(COST, COST, 0x101);                            \
        ppv = (j >= 10) ? COST : ppv;                                       \
        float best = fminf(fminf(pm, COST), ppv);                           \
        int sel = (pm == best) ? sel0 : ((COST == best) ? 1 : 2);           \
        COST = best - BUF[rr];                                              \
        unsigned long long bb0 = __ballot(sel & 1);                         \
        unsigned long long bb1 = __ballot(sel & 2);                         \
        if (j == 0) CH[grp][(rbase) + rr] =                                 \
            (uint32_t)(((bb0 >> shb) & 0xFFFFull) |                         \
                       (((bb1 >> shb) & 0xFFFFull) << 16));                 \
    }

// interleaved pair: row of A then row of B (chains overlap in stall shadows)
#define PROC2(BA, BBF, cbase)                                               \
    _Pragma("unroll")                                                       \
    for (int rr = 0; rr < 16; ++rr) {                                       \
        RS(BA, rr, (cbase) * 16, cost_a, chA)                               \
        RS(BBF, rr, (cbase) * 16, cost_b, chB)                              \
    }

    // prologue: chunks 0,1 in flight for both DPs
    LOAD0(a0, 0);
    LOAD1(b0_, 0);
    LOAD0(a1, 1);
    LOAD1(b1_, 1);
    cost_a = -a0[0];
    cost_b = -b0_[0];
#pragma unroll
    for (int rr = 1; rr < 16; ++rr) {
        RS(a0, rr, 0, cost_a, chA)
        RS(b0_, rr, 0, cost_b, chB)
    }
    LOAD0(a0, 2);
    LOAD1(b0_, 2);
    PROC2(a1, b1_, 1);
    LOAD0(a1, 3);
    LOAD1(b1_, 3);

#pragma unroll 1
    for (int c2 = 2; c2 <= 12; c2 += 2) {
        PROC2(a0, b0_, c2);
        if (c2 + 2 < 14) { LOAD0(a0, c2 + 2); LOAD1(b0_, c2 + 2); }
        PROC2(a1, b1_, c2 + 1);
        if (c2 + 3 < 14) { LOAD0(a1, c2 + 3); LOAD1(b1_, c2 + 3); }
    }

    // final argmin per DP (first-min == lexicographic min), interleaved
    float rcA = (j <= 10) ? cost_a : INFINITY;
    int   riA = (j <= 10) ? j : 15;
    float rcB = (j <= 10) ? cost_b : INFINITY;
    int   riB = (j <= 10) ? j : 15;
#define REDSTEP(ctrl)                                                        \
    {                                                                        \
        float oc = DPPF_Z(rcA, ctrl); int oi = DPPI_Z(riA, ctrl);            \
        bool t = (oc < rcA) || (oc == rcA && oi < riA);                      \
        rcA = t ? oc : rcA; riA = t ? oi : riA;                              \
        float od = DPPF_Z(rcB, ctrl); int oj2 = DPPI_Z(riB, ctrl);           \
        bool u = (od < rcB) || (od == rcB && oj2 < riB);                     \
        rcB = u ? od : rcB; riB = u ? oj2 : riB;                             \
    }
    REDSTEP(0x128) REDSTEP(0x124) REDSTEP(0x122) REDSTEP(0x121)
#undef REDSTEP

    int posA = riA, posB = riB;
    if (j == 0) {
        pthA[grp][HH - 1] = band0 + posA;
        pthB[grp][HH - 1] = band0 + posB;
    }

    // backtrack: both pos chains interleaved; w words prefetched per chunk
#pragma unroll 1
    for (int c = 13; c >= 0; --c) {
        uint32_t wA[16], wB[16];
#pragma unroll
        for (int rr = 0; rr < 16; ++rr) {
            wA[rr] = chA[grp][c * 16 + rr];
            wB[rr] = chB[grp][c * 16 + rr];
        }
#pragma unroll
        for (int rr = 15; rr >= 0; --rr) {
            int r = c * 16 + rr;
            if (r >= 1) {
                uint32_t wa = wA[rr], wb = wB[rr];
                int selA = (int)((wa >> posA) & 1u) | (int)((wa >> (posA + 15)) & 2u);
                int selB = (int)((wb >> posB) & 1u) | (int)((wb >> (posB + 15)) & 2u);
                posA += selA - 1;
                posB += selB - 1;
                if (j == 0) {
                    pthA[grp][r - 1] = band0 + posA;
                    pthB[grp][r - 1] = band0 + posB;
                }
            }
        }
    }

    // coalesced path writes; layout [b][dir*7+p][224]
    int* opA = paths + (size_t)(b * 14 + p) * HH;
    int* opB = paths + (size_t)(b * 14 + NSEAM + p) * HH;
#pragma unroll 1
    for (int c = 0; c < 14; ++c) {
        opA[c * 16 + j] = pthA[grp][c * 16 + j];
        opB[c * 16 + j] = pthB[grp][c * 16 + j];
    }

#undef LOAD0
#undef LOAD1
#undef RS
#undef PROC2
}

// ---------------------------------------------------------------------------
// Kernel 2: labels + centroid partials (R13-proven, unchanged). Grid = B*8.
// 3-segment static walk; vl = basev + (in-band && pv[y][kv] <= x).
// Run-length flush -> packed u64 LDS atomic; block partials -> global
// atomicAdd. Fields cnt:22@42 / sy:21@21 / sx:21@0, carry-free; all
// integers < 2^22 exact in f32.
// ---------------------------------------------------------------------------
__global__ __launch_bounds__(256) void label_kernel(const int* __restrict__ paths,
                                                    float* __restrict__ out,
                                                    unsigned long long* __restrict__ gacc) {
    const int b  = blockIdx.x >> 3;
    const int cy = blockIdx.x & 7;
    const int y0 = cy * YROWS;

    __shared__ unsigned char vpc[NSEAM][YROWS];
    __shared__ unsigned long long acc[KK];

    const int* pb = paths + (size_t)b * 14 * HH;
    for (int i = threadIdx.x; i < NSEAM * YROWS; i += 256) {
        int q = i / YROWS, r = i - q * YROWS;
        vpc[q][r] = (unsigned char)pb[q * HH + y0 + r];
    }
    if (threadIdx.x < KK) acc[threadIdx.x] = 0ull;
    __syncthreads();

    const int x = threadIdx.x;
    if (x < WW) {
        int basev = 0, kv = 0, inv = 0;
        if (x >= 23) {
            int q = x - 23, k = q / 28, r = q - k * 28;
            if (k > 6) basev = 7;
            else { inv = (r <= 10) ? 1 : 0; basev = k + (r > 10 ? 1 : 0); kv = k; }
        }
        const int hA = (cy >= 1) ? pb[(NSEAM + cy - 1) * HH + x] : 0;
        const int hB = (cy <= 6) ? pb[(NSEAM + cy) * HH + x] : 0;

        float* mb = out + (size_t)BB * KK * 2 + (size_t)b * HH * WW + x;
        int cur = -1, ys = y0;

#define FLUSH(yend)                                                          \
        {                                                                    \
            unsigned cnt = (unsigned)((yend) - ys);                          \
            unsigned sy  = (unsigned)((ys + (yend) - 1) * ((yend) - ys) / 2);\
            unsigned sx  = (unsigned)x * cnt;                                \
            atomicAdd(&acc[cur], ((unsigned long long)cnt << 42) |           \
                                 ((unsigned long long)sy << 21) |            \
                                 (unsigned long long)sx);                    \
        }
#define ROW(t, HLEXPR)                                                       \
        {                                                                    \
            const int y = y0 + (t);                                          \
            int vl = basev + ((inv && (int)vpc[kv][t] <= x) ? 1 : 0);        \
            int lab = vl + 8 * (HLEXPR);                                     \
            mb[y * WW] = (float)lab;                                         \
            if (lab != cur) { if (cur >= 0) FLUSH(y); cur = lab; ys = y; }   \
        }
#pragma unroll
        for (int t = 0; t < 6; ++t)
            ROW(t, (cy >= 1) ? (cy - 1 + ((hA <= y0 + t) ? 1 : 0)) : 0)
#pragma unroll
        for (int t = 6; t < 23; ++t)
            ROW(t, cy)
#pragma unroll
        for (int t = 23; t < 28; ++t)
            ROW(t, (cy <= 6) ? (cy + ((hB <= y0 + t) ? 1 : 0)) : 7)
        FLUSH(y0 + YROWS)
#undef ROW
#undef FLUSH
    }
    __syncthreads();

    if (threadIdx.x < KK) {
        unsigned long long v = acc[threadIdx.x];
        if (v) atomicAdd(&gacc[(size_t)b * KK + threadIdx.x], v);
    }
}

// ---------------------------------------------------------------------------
// Kernel 3: finalize centroids. 16384 regions; unpack, divide, float2 store.
// ---------------------------------------------------------------------------
__global__ __launch_bounds__(256) void finalize_kernel(const unsigned long long* __restrict__ gacc,
                                                       float* __restrict__ out) {
    int i = blockIdx.x * 256 + threadIdx.x;
    unsigned long long sv = gacc[i];
    float cnt = (float)(unsigned)(sv >> 42);
    float sy  = (float)(unsigned)((sv >> 21) & 0x1FFFFFu);
    float sx  = (float)(unsigned)(sv & 0x1FFFFFu);
    float c = fmaxf(cnt, 1e-6f);
    float2 r; r.x = sy / c; r.y = sx / c;
    *reinterpret_cast<float2*>(out + (size_t)i * 2) = r;
}

extern "C" void kernel_launch(void* const* d_in, const int* in_sizes, int n_in,
                              void* d_out, int out_size, void* d_ws, size_t ws_size,
                              hipStream_t stream) {
    const float* g = (const float*)d_in[1];
    float* out = (float*)d_out;
    int* paths = (int*)d_ws;                                        // 3,211,264 B
    unsigned long long* gacc =
        (unsigned long long*)((char*)d_ws + (size_t)BB * 14 * HH * 4);   // 128 KiB

    dp_kernel<<<(BB * NSEAM) / 16, 256, 0, stream>>>(g, paths, gacc);   // 112 blocks
    label_kernel<<<BB * YCH, 256, 0, stream>>>(paths, out, gacc);
    finalize_kernel<<<(BB * KK) / 256, 256, 0, stream>>>(gacc, out);
}

// Round 19
// 50.259 us; speedup vs baseline: 32.5632x; 1.3542x over previous
//
#include <hip/hip_runtime.h>
#include <stdint.h>

#define HH 224
#define WW 224
#define NSEAM 7
#define BWIDTH 5
#define BB 256
#define KK 64
#define YCH 8
#define YROWS (HH / YCH)

// DPP helpers (ctrl must be literal): row_shr:1=0x111 (dst[i]=src[i-1]),
// row_shl:1=0x101 (dst[i]=src[i+1]). Rows = 16 lanes.
#define DPPF_OLD(old, src, ctrl) \
    __int_as_float(__builtin_amdgcn_update_dpp(__float_as_int(old), __float_as_int(src), ctrl, 0xF, 0xF, false))
#define DPPF_Z(src, ctrl) \
    __int_as_float(__builtin_amdgcn_update_dpp(0, __float_as_int(src), ctrl, 0xF, 0xF, true))
#define DPPI_Z(src, ctrl) \
    __builtin_amdgcn_update_dpp(0, (int)(src), ctrl, 0xF, 0xF, true)

// ---------------------------------------------------------------------------
// Kernel 1: seam DP, split-phase. R17 probes: the old fused row step cost
// ~236 cyc/row because sel/ballot/exec-masked-store rode the serial chain.
// Now: FWD pass = minimal chain (dpp,dpp,clip,min,min,sub + reg copy to
// hist[]), ~5 VALU/row; SEL pass recomputes sel from hist (IDENTICAL
// comparisons -> identical backtrack) with rows independent -> 16-deep ILP,
// and SEL(c) interleaves with FWD(c+1). 224 blocks (R18's halved grid
// reverted). Loads/argmin/backtrack/store = R13-proven. Zeroes gacc.
// ---------------------------------------------------------------------------
__global__ __launch_bounds__(256) void dp_kernel(const float* __restrict__ g,
                                                 int* __restrict__ paths,
                                                 unsigned long long* __restrict__ gacc) {
    __shared__ uint32_t ch[16][226];   // per-row packed sel bits (b0 | b1<<16)
    __shared__ int      pth[16][226];  // backtracked path positions

    {   // zero global centroid accumulators (label kernel runs after us)
        int t = blockIdx.x * 256 + threadIdx.x;
        if (t < BB * KK) gacc[t] = 0ull;
    }

    const int j   = threadIdx.x & 15;
    const int grp = threadIdx.x >> 4;
    const int gid = blockIdx.x * 16 + grp;
    const int dir = gid / (BB * NSEAM);         // block-uniform (1792/16=112)
    const int rem = gid - dir * (BB * NSEAM);
    const int b   = rem / NSEAM;
    const int p   = rem - b * NSEAM;
    const int band0 = 28 * (p + 1) - BWIDTH;
    const int jc  = (j > 10) ? 10 : j;          // clamp junk lanes
    const float* gb  = g + (size_t)b * HH * WW;
    const float* gp0 = gb + band0 + jc;                 // dir0: strided rows
    const float* gp1 = gb + (size_t)(band0 + jc) * WW;  // dir1: contiguous cols
    const int shb  = threadIdx.x & 48;          // this group's ballot slice
    const int sel0 = (j == 0) ? 1 : 0;          // sel when jm candidate wins

    float bufA[16], bufB[16];                   // even / odd chunk g-values
    float hE[16], hO[16];                       // even / odd chunk cost hist
    float cost;

#define LOADC(BUF, c)                                                       \
    if (dir == 0) {                                                         \
        _Pragma("unroll")                                                   \
        for (int rr = 0; rr < 16; ++rr) BUF[rr] = gp0[((c) * 16 + rr) * WW];\
    } else {                                                                \
        const float4* q4 = reinterpret_cast<const float4*>(gp1 + (c) * 16); \
        float4 t0 = q4[0], t1 = q4[1], t2 = q4[2], t3 = q4[3];              \
        BUF[0] = t0.x;  BUF[1] = t0.y;  BUF[2] = t0.z;  BUF[3] = t0.w;      \
        BUF[4] = t1.x;  BUF[5] = t1.y;  BUF[6] = t1.z;  BUF[7] = t1.w;      \
        BUF[8] = t2.x;  BUF[9] = t2.y;  BUF[10] = t2.z; BUF[11] = t2.w;     \
        BUF[12] = t3.x; BUF[13] = t3.y; BUF[14] = t3.z; BUF[15] = t3.w;     \
    }

// FWD: minimal serial chain; arithmetic byte-identical to R13's ROWSTEP
// (fminf(fminf(pm,cost),ppv) - g).
#define FWDSTEP(BUF, HIST, rr)                                              \
    {                                                                       \
        float pm  = DPPF_OLD(cost, cost, 0x111);                            \
        float pv  = DPPF_OLD(cost, cost, 0x101);                            \
        pv = (j >= 10) ? cost : pv;                                         \
        cost = fminf(fminf(pm, cost), pv) - BUF[rr];                        \
        HIST[rr] = cost;                                                    \
    }

#define FWDC(BUF, HIST)                                                     \
    _Pragma("unroll")                                                       \
    for (int rr = 0; rr < 16; ++rr) FWDSTEP(BUF, HIST, rr)

// SEL: recompute sel for row (rbase+rr) from prev-row cost (hist / carry);
// identical comparisons to R13 -> identical sel; rows independent (ILP).
#define SELSTEP(HIST, CARRY, rr, rbase)                                     \
    {                                                                       \
        float prev = (rr == 0) ? (CARRY) : HIST[(rr == 0) ? 0 : rr - 1];    \
        float pm  = DPPF_OLD(prev, prev, 0x111);                            \
        float pv  = DPPF_OLD(prev, prev, 0x101);                            \
        pv = (j >= 10) ? prev : pv;                                         \
        float best = fminf(fminf(pm, prev), pv);                            \
        int sel = (pm == best) ? sel0 : ((prev == best) ? 1 : 2);           \
        unsigned long long bb0 = __ballot(sel & 1);                         \
        unsigned long long bb1 = __ballot(sel & 2);                         \
        if (j == 0) ch[grp][(rbase) + rr] =                                 \
            (uint32_t)(((bb0 >> shb) & 0xFFFFull) |                         \
                       (((bb1 >> shb) & 0xFFFFull) << 16));                 \
    }

#define SELC(HIST, CARRY, cbase)                                            \
    _Pragma("unroll")                                                       \
    for (int rr = 0; rr < 16; ++rr) SELSTEP(HIST, CARRY, rr, (cbase) * 16)

    // ---- prologue: chunks 0,1 ----
    LOADC(bufA, 0);
    LOADC(bufB, 1);
    cost = -bufA[0];
    hE[0] = cost;
#pragma unroll
    for (int rr = 1; rr < 16; ++rr) FWDSTEP(bufA, hE, rr);
    LOADC(bufA, 2);
    FWDC(bufB, hO);                    // chunk 1
    SELC(hE, 0.0f, 0);                 // chunk 0 (row 0's sel: garbage, unread)
    LOADC(bufB, 3);

    // ---- main: 2 chunks/iter; SEL(k) scheduled beside FWD(k+1) ----
#pragma unroll 1
    for (int c2 = 2; c2 <= 12; c2 += 2) {
        float carA = hE[15];           // tail(c2-2) -> carry for SEL(c2-1)
        FWDC(bufA, hE);                // chunk c2 (overwrites hE)
        SELC(hO, carA, c2 - 1);        // chunk c2-1 (independent of FWD above)
        float carB = hO[15];           // tail(c2-1) -> carry for SEL(c2)
        if (c2 + 2 < 14) LOADC(bufA, c2 + 2);
        FWDC(bufB, hO);                // chunk c2+1
        SELC(hE, carB, c2);            // chunk c2
        if (c2 + 3 < 14) LOADC(bufB, c2 + 3);
    }
    SELC(hO, hE[15], 13);              // chunk 13 (carry = tail(12))

    // final argmin across 11 lanes, first-min tie-break == lexicographic min
    float rc = (j <= 10) ? cost : INFINITY;
    int   ri = (j <= 10) ? j : 15;
#define REDSTEP(ctrl)                                                        \
    {                                                                        \
        float oc = DPPF_Z(rc, ctrl);                                         \
        int   oi = DPPI_Z(ri, ctrl);                                         \
        bool t = (oc < rc) || (oc == rc && oi < ri);                         \
        rc = t ? oc : rc; ri = t ? oi : ri;                                  \
    }
    REDSTEP(0x128) REDSTEP(0x124) REDSTEP(0x122) REDSTEP(0x121)
#undef REDSTEP

    int pos = ri;
    if (j == 0) pth[grp][HH - 1] = band0 + pos;

    // backtrack: broadcast LDS reads prefetched per chunk; ~4 VALU/row chain
#pragma unroll 1
    for (int c = 13; c >= 0; --c) {
        uint32_t w[16];
#pragma unroll
        for (int rr = 0; rr < 16; ++rr) w[rr] = ch[grp][c * 16 + rr];
#pragma unroll
        for (int rr = 15; rr >= 0; --rr) {
            int r = c * 16 + rr;
            if (r >= 1) {
                uint32_t ww = w[rr];
                int sel = (int)((ww >> pos) & 1u) | (int)((ww >> (pos + 15)) & 2u);
                pos += sel - 1;
                if (j == 0) pth[grp][r - 1] = band0 + pos;
            }
        }
    }

    // coalesced path write; layout [b][dir*7+p][224]
    int* op = paths + (size_t)(b * 14 + dir * NSEAM + p) * HH;
#pragma unroll 1
    for (int c = 0; c < 14; ++c) op[c * 16 + j] = pth[grp][c * 16 + j];

#undef LOADC
#undef FWDSTEP
#undef FWDC
#undef SELSTEP
#undef SELC
}

// ---------------------------------------------------------------------------
// Kernel 2: labels + centroid partials (R13-proven, unchanged). Grid = B*8.
// 3-segment static walk; vl = basev + (in-band && pv[y][kv] <= x).
// Run-length flush -> packed u64 LDS atomic; block partials -> global
// atomicAdd. Fields cnt:22@42 / sy:21@21 / sx:21@0, carry-free; all
// integers < 2^22 exact in f32.
// ---------------------------------------------------------------------------
__global__ __launch_bounds__(256) void label_kernel(const int* __restrict__ paths,
                                                    float* __restrict__ out,
                                                    unsigned long long* __restrict__ gacc) {
    const int b  = blockIdx.x >> 3;
    const int cy = blockIdx.x & 7;
    const int y0 = cy * YROWS;

    __shared__ unsigned char vpc[NSEAM][YROWS];
    __shared__ unsigned long long acc[KK];

    const int* pb = paths + (size_t)b * 14 * HH;
    for (int i = threadIdx.x; i < NSEAM * YROWS; i += 256) {
        int q = i / YROWS, r = i - q * YROWS;
        vpc[q][r] = (unsigned char)pb[q * HH + y0 + r];
    }
    if (threadIdx.x < KK) acc[threadIdx.x] = 0ull;
    __syncthreads();

    const int x = threadIdx.x;
    if (x < WW) {
        int basev = 0, kv = 0, inv = 0;
        if (x >= 23) {
            int q = x - 23, k = q / 28, r = q - k * 28;
            if (k > 6) basev = 7;
            else { inv = (r <= 10) ? 1 : 0; basev = k + (r > 10 ? 1 : 0); kv = k; }
        }
        const int hA = (cy >= 1) ? pb[(NSEAM + cy - 1) * HH + x] : 0;
        const int hB = (cy <= 6) ? pb[(NSEAM + cy) * HH + x] : 0;

        float* mb = out + (size_t)BB * KK * 2 + (size_t)b * HH * WW + x;
        int cur = -1, ys = y0;

#define FLUSH(yend)                                                          \
        {                                                                    \
            unsigned cnt = (unsigned)((yend) - ys);                          \
            unsigned sy  = (unsigned)((ys + (yend) - 1) * ((yend) - ys) / 2);\
            unsigned sx  = (unsigned)x * cnt;                                \
            atomicAdd(&acc[cur], ((unsigned long long)cnt << 42) |           \
                                 ((unsigned long long)sy << 21) |            \
                                 (unsigned long long)sx);                    \
        }
#define ROW(t, HLEXPR)                                                       \
        {                                                                    \
            const int y = y0 + (t);                                          \
            int vl = basev + ((inv && (int)vpc[kv][t] <= x) ? 1 : 0);        \
            int lab = vl + 8 * (HLEXPR);                                     \
            mb[y * WW] = (float)lab;                                         \
            if (lab != cur) { if (cur >= 0) FLUSH(y); cur = lab; ys = y; }   \
        }
#pragma unroll
        for (int t = 0; t < 6; ++t)
            ROW(t, (cy >= 1) ? (cy - 1 + ((hA <= y0 + t) ? 1 : 0)) : 0)
#pragma unroll
        for (int t = 6; t < 23; ++t)
            ROW(t, cy)
#pragma unroll
        for (int t = 23; t < 28; ++t)
            ROW(t, (cy <= 6) ? (cy + ((hB <= y0 + t) ? 1 : 0)) : 7)
        FLUSH(y0 + YROWS)
#undef ROW
#undef FLUSH
    }
    __syncthreads();

    if (threadIdx.x < KK) {
        unsigned long long v = acc[threadIdx.x];
        if (v) atomicAdd(&gacc[(size_t)b * KK + threadIdx.x], v);
    }
}

// ---------------------------------------------------------------------------
// Kernel 3: finalize centroids. 16384 regions; unpack, divide, float2 store.
// ---------------------------------------------------------------------------
__global__ __launch_bounds__(256) void finalize_kernel(const unsigned long long* __restrict__ gacc,
                                                       float* __restrict__ out) {
    int i = blockIdx.x * 256 + threadIdx.x;
    unsigned long long sv = gacc[i];
    float cnt = (float)(unsigned)(sv >> 42);
    float sy  = (float)(unsigned)((sv >> 21) & 0x1FFFFFu);
    float sx  = (float)(unsigned)(sv & 0x1FFFFFu);
    float c = fmaxf(cnt, 1e-6f);
    float2 r; r.x = sy / c; r.y = sx / c;
    *reinterpret_cast<float2*>(out + (size_t)i * 2) = r;
}

extern "C" void kernel_launch(void* const* d_in, const int* in_sizes, int n_in,
                              void* d_out, int out_size, void* d_ws, size_t ws_size,
                              hipStream_t stream) {
    const float* g = (const float*)d_in[1];
    float* out = (float*)d_out;
    int* paths = (int*)d_ws;                                        // 3,211,264 B
    unsigned long long* gacc =
        (unsigned long long*)((char*)d_ws + (size_t)BB * 14 * HH * 4);   // 128 KiB

    dp_kernel<<<(BB * 14) / 16, 256, 0, stream>>>(g, paths, gacc);  // 224 blocks
    label_kernel<<<BB * YCH, 256, 0, stream>>>(paths, out, gacc);
    finalize_kernel<<<(BB * KK) / 256, 256, 0, stream>>>(gacc, out);
}

// Round 20
// 45.530 us; speedup vs baseline: 35.9451x; 1.1039x over previous
//
#include <hip/hip_runtime.h>
#include <stdint.h>

#define HH 224
#define WW 224
#define NSEAM 7
#define BWIDTH 5
#define BB 256
#define KK 64
#define YCH 8
#define YROWS (HH / YCH)

// DPP helpers (ctrl must be literal): row_shr:1=0x111 (dst[i]=src[i-1]),
// row_shl:1=0x101 (dst[i]=src[i+1]). Rows = 16 lanes.
#define DPPF_OLD(old, src, ctrl) \
    __int_as_float(__builtin_amdgcn_update_dpp(__float_as_int(old), __float_as_int(src), ctrl, 0xF, 0xF, false))
#define DPPF_Z(src, ctrl) \
    __int_as_float(__builtin_amdgcn_update_dpp(0, __float_as_int(src), ctrl, 0xF, 0xF, true))
#define DPPI_Z(src, ctrl) \
    __builtin_amdgcn_update_dpp(0, (int)(src), ctrl, 0xF, 0xF, true)

// ---------------------------------------------------------------------------
// Kernel 1: seam DP. R17-19 diagnosis: per-row cost was the BALLOT machinery
// (2 wave-level ballots + 64b variable shifts + exec-masked store ~20 ops/row),
// not the float chain. Now: per-row sel bits via 2 cmp + 2 cndmask packed
// in-register with lshl_or (12 VALU/row, 0 SALU, 0 exec); once per 16-row
// chunk a 4-stage ds_swizzle XOR butterfly transposes the two 16x16 bit
// planes into the EXACT per-row word format (b0 | b1<<16) the proven
// backtrack reads — all 16 lanes store one row-word each, no exec mask.
// sel semantics bit-identical to R13 (absmax=0): sel = b0 + 2*b1 =
// (pm==best) ? sel0 : ((cost==best) ? 1 : 2). Loads/argmin/backtrack/store
// = R13-proven. 224 blocks. Zeroes gacc.
// ---------------------------------------------------------------------------
__global__ __launch_bounds__(256) void dp_kernel(const float* __restrict__ g,
                                                 int* __restrict__ paths,
                                                 unsigned long long* __restrict__ gacc) {
    __shared__ uint32_t ch[16][226];   // per-row packed sel bits (b0 | b1<<16)
    __shared__ int      pth[16][226];  // backtracked path positions

    {   // zero global centroid accumulators (label kernel runs after us)
        int t = blockIdx.x * 256 + threadIdx.x;
        if (t < BB * KK) gacc[t] = 0ull;
    }

    const int j   = threadIdx.x & 15;
    const int grp = threadIdx.x >> 4;
    const int gid = blockIdx.x * 16 + grp;
    const int dir = gid / (BB * NSEAM);         // block-uniform (1792/16=112)
    const int rem = gid - dir * (BB * NSEAM);
    const int b   = rem / NSEAM;
    const int p   = rem - b * NSEAM;
    const int band0 = 28 * (p + 1) - BWIDTH;
    const int jc  = (j > 10) ? 10 : j;          // clamp junk lanes
    const float* gb  = g + (size_t)b * HH * WW;
    const float* gp0 = gb + band0 + jc;                 // dir0: strided rows
    const float* gp1 = gb + (size_t)(band0 + jc) * WW;  // dir1: contiguous cols
    const unsigned isj0 = (j == 0) ? 1u : 0u;   // sel bit0 when jm wins at j==0

    float bufA[16], bufB[16], cost;

#define LOADC(BUF, c)                                                       \
    if (dir == 0) {                                                         \
        _Pragma("unroll")                                                   \
        for (int rr = 0; rr < 16; ++rr) BUF[rr] = gp0[((c) * 16 + rr) * WW];\
    } else {                                                                \
        const float4* q4 = reinterpret_cast<const float4*>(gp1 + (c) * 16); \
        float4 t0 = q4[0], t1 = q4[1], t2 = q4[2], t3 = q4[3];              \
        BUF[0] = t0.x;  BUF[1] = t0.y;  BUF[2] = t0.z;  BUF[3] = t0.w;      \
        BUF[4] = t1.x;  BUF[5] = t1.y;  BUF[6] = t1.z;  BUF[7] = t1.w;      \
        BUF[8] = t2.x;  BUF[9] = t2.y;  BUF[10] = t2.z; BUF[11] = t2.w;     \
        BUF[12] = t3.x; BUF[13] = t3.y; BUF[14] = t3.z; BUF[15] = t3.w;     \
    }

// one DP row: min-chain + 2 sel bits accumulated in-register.
// bit-exact R13 semantics: best = fminf(fminf(pm,cost),ppv);
// b0 = pm==best ? isj0 : (cost==best); b1 = pm==best ? 0 : !(cost==best).
#define ROWSEL(BUF, rr)                                                     \
    {                                                                       \
        float pm  = DPPF_OLD(cost, cost, 0x111);                            \
        float pv  = DPPF_OLD(cost, cost, 0x101);                            \
        pv = (j >= 10) ? cost : pv;                                         \
        float best = fminf(fminf(pm, cost), pv);                            \
        unsigned cc = (cost == best) ? 1u : 0u;                             \
        unsigned b0 = (pm == best) ? isj0 : cc;                             \
        unsigned b1 = (pm == best) ? 0u : (cc ^ 1u);                        \
        cost = best - (BUF)[rr];                                            \
        selLo |= b0 << (rr);                                                \
        selHi |= b1 << (rr);                                                \
    }

// 16x16 1-bit-plane transpose across the 16 lanes of a group:
// after TR16, lane r bit q == (orig lane q bit r). 4-stage XOR butterfly;
// verified: stage s swaps the s-distance sub-blocks (2x2/4x4 hand-checked).
#define TR16(x)                                                             \
    {                                                                       \
        unsigned pp;                                                        \
        pp = (unsigned)__builtin_amdgcn_ds_swizzle((int)(x), 0x201F);       \
        x = (j & 8) ? ((x & 0xFF00u) | ((pp >> 8) & 0x00FFu))               \
                    : ((x & 0x00FFu) | ((pp << 8) & 0xFF00u));              \
        pp = (unsigned)__builtin_amdgcn_ds_swizzle((int)(x), 0x101F);       \
        x = (j & 4) ? ((x & 0xF0F0u) | ((pp >> 4) & 0x0F0Fu))               \
                    : ((x & 0x0F0Fu) | ((pp << 4) & 0xF0F0u));              \
        pp = (unsigned)__builtin_amdgcn_ds_swizzle((int)(x), 0x081F);       \
        x = (j & 2) ? ((x & 0xCCCCu) | ((pp >> 2) & 0x3333u))               \
                    : ((x & 0x3333u) | ((pp << 2) & 0xCCCCu));              \
        pp = (unsigned)__builtin_amdgcn_ds_swizzle((int)(x), 0x041F);       \
        x = (j & 1) ? ((x & 0xAAAAu) | ((pp >> 1) & 0x5555u))               \
                    : ((x & 0x5555u) | ((pp << 1) & 0xAAAAu));              \
    }

// full 16-row chunk: accumulate sel planes, transpose, store row-words.
// lane r's word covers row c*16+r; bits 11-15 come from junk lanes but are
// never read (pos <= 10). Row 0's word (c==0, lane 0) is unread by backtrack.
#define PROCC(BUF, c)                                                       \
    {                                                                       \
        unsigned selLo = 0u, selHi = 0u;                                    \
        _Pragma("unroll")                                                   \
        for (int rr = 0; rr < 16; ++rr) ROWSEL(BUF, rr)                     \
        TR16(selLo)                                                         \
        TR16(selHi)                                                         \
        ch[grp][(c) * 16 + j] = selLo | (selHi << 16);                      \
    }

    // ---- prologue: chunks 0 (row-0 init) and 1; loads 2 chunks ahead ----
    LOADC(bufA, 0);
    LOADC(bufB, 1);
    {
        unsigned selLo = 0u, selHi = 0u;
        cost = -bufA[0];
#pragma unroll
        for (int rr = 1; rr < 16; ++rr) ROWSEL(bufA, rr)
        TR16(selLo)
        TR16(selHi)
        ch[grp][j] = selLo | (selHi << 16);
    }
    LOADC(bufA, 2);
    PROCC(bufB, 1);
    LOADC(bufB, 3);

#pragma unroll 1
    for (int c2 = 2; c2 <= 12; c2 += 2) {
        PROCC(bufA, c2);
        if (c2 + 2 < 14) LOADC(bufA, c2 + 2);
        PROCC(bufB, c2 + 1);
        if (c2 + 3 < 14) LOADC(bufB, c2 + 3);
    }

    // final argmin across 11 lanes, first-min tie-break == lexicographic min
    float rc = (j <= 10) ? cost : INFINITY;
    int   ri = (j <= 10) ? j : 15;
#define REDSTEP(ctrl)                                                        \
    {                                                                        \
        float oc = DPPF_Z(rc, ctrl);                                         \
        int   oi = DPPI_Z(ri, ctrl);                                         \
        bool t = (oc < rc) || (oc == rc && oi < ri);                         \
        rc = t ? oc : rc; ri = t ? oi : ri;                                  \
    }
    REDSTEP(0x128) REDSTEP(0x124) REDSTEP(0x122) REDSTEP(0x121)
#undef REDSTEP

    int pos = ri;
    if (j == 0) pth[grp][HH - 1] = band0 + pos;

    // backtrack (R13-proven): broadcast LDS reads prefetched per chunk
#pragma unroll 1
    for (int c = 13; c >= 0; --c) {
        uint32_t w[16];
#pragma unroll
        for (int rr = 0; rr < 16; ++rr) w[rr] = ch[grp][c * 16 + rr];
#pragma unroll
        for (int rr = 15; rr >= 0; --rr) {
            int r = c * 16 + rr;
            if (r >= 1) {
                uint32_t ww = w[rr];
                int sel = (int)((ww >> pos) & 1u) | (int)((ww >> (pos + 15)) & 2u);
                pos += sel - 1;
                if (j == 0) pth[grp][r - 1] = band0 + pos;
            }
        }
    }

    // coalesced path write; layout [b][dir*7+p][224]
    int* op = paths + (size_t)(b * 14 + dir * NSEAM + p) * HH;
#pragma unroll 1
    for (int c = 0; c < 14; ++c) op[c * 16 + j] = pth[grp][c * 16 + j];

#undef LOADC
#undef ROWSEL
#undef TR16
#undef PROCC
}

// ---------------------------------------------------------------------------
// Kernel 2: labels + centroid partials (R13-proven, unchanged). Grid = B*8.
// 3-segment static walk; vl = basev + (in-band && pv[y][kv] <= x).
// Run-length flush -> packed u64 LDS atomic; block partials -> global
// atomicAdd. Fields cnt:22@42 / sy:21@21 / sx:21@0, carry-free; all
// integers < 2^22 exact in f32.
// ---------------------------------------------------------------------------
__global__ __launch_bounds__(256) void label_kernel(const int* __restrict__ paths,
                                                    float* __restrict__ out,
                                                    unsigned long long* __restrict__ gacc) {
    const int b  = blockIdx.x >> 3;
    const int cy = blockIdx.x & 7;
    const int y0 = cy * YROWS;

    __shared__ unsigned char vpc[NSEAM][YROWS];
    __shared__ unsigned long long acc[KK];

    const int* pb = paths + (size_t)b * 14 * HH;
    for (int i = threadIdx.x; i < NSEAM * YROWS; i += 256) {
        int q = i / YROWS, r = i - q * YROWS;
        vpc[q][r] = (unsigned char)pb[q * HH + y0 + r];
    }
    if (threadIdx.x < KK) acc[threadIdx.x] = 0ull;
    __syncthreads();

    const int x = threadIdx.x;
    if (x < WW) {
        int basev = 0, kv = 0, inv = 0;
        if (x >= 23) {
            int q = x - 23, k = q / 28, r = q - k * 28;
            if (k > 6) basev = 7;
            else { inv = (r <= 10) ? 1 : 0; basev = k + (r > 10 ? 1 : 0); kv = k; }
        }
        const int hA = (cy >= 1) ? pb[(NSEAM + cy - 1) * HH + x] : 0;
        const int hB = (cy <= 6) ? pb[(NSEAM + cy) * HH + x] : 0;

        float* mb = out + (size_t)BB * KK * 2 + (size_t)b * HH * WW + x;
        int cur = -1, ys = y0;

#define FLUSH(yend)                                                          \
        {                                                                    \
            unsigned cnt = (unsigned)((yend) - ys);                          \
            unsigned sy  = (unsigned)((ys + (yend) - 1) * ((yend) - ys) / 2);\
            unsigned sx  = (unsigned)x * cnt;                                \
            atomicAdd(&acc[cur], ((unsigned long long)cnt << 42) |           \
                                 ((unsigned long long)sy << 21) |            \
                                 (unsigned long long)sx);                    \
        }
#define ROW(t, HLEXPR)                                                       \
        {                                                                    \
            const int y = y0 + (t);                                          \
            int vl = basev + ((inv && (int)vpc[kv][t] <= x) ? 1 : 0);        \
            int lab = vl + 8 * (HLEXPR);                                     \
            mb[y * WW] = (float)lab;                                         \
            if (lab != cur) { if (cur >= 0) FLUSH(y); cur = lab; ys = y; }   \
        }
#pragma unroll
        for (int t = 0; t < 6; ++t)
            ROW(t, (cy >= 1) ? (cy - 1 + ((hA <= y0 + t) ? 1 : 0)) : 0)
#pragma unroll
        for (int t = 6; t < 23; ++t)
            ROW(t, cy)
#pragma unroll
        for (int t = 23; t < 28; ++t)
            ROW(t, (cy <= 6) ? (cy + ((hB <= y0 + t) ? 1 : 0)) : 7)
        FLUSH(y0 + YROWS)
#undef ROW
#undef FLUSH
    }
    __syncthreads();

    if (threadIdx.x < KK) {
        unsigned long long v = acc[threadIdx.x];
        if (v) atomicAdd(&gacc[(size_t)b * KK + threadIdx.x], v);
    }
}

// ---------------------------------------------------------------------------
// Kernel 3: finalize centroids. 16384 regions; unpack, divide, float2 store.
// ---------------------------------------------------------------------------
__global__ __launch_bounds__(256) void finalize_kernel(const unsigned long long* __restrict__ gacc,
                                                       float* __restrict__ out) {
    int i = blockIdx.x * 256 + threadIdx.x;
    unsigned long long sv = gacc[i];
    float cnt = (float)(unsigned)(sv >> 42);
    float sy  = (float)(unsigned)((sv >> 21) & 0x1FFFFFu);
    float sx  = (float)(unsigned)(sv & 0x1FFFFFu);
    float c = fmaxf(cnt, 1e-6f);
    float2 r; r.x = sy / c; r.y = sx / c;
    *reinterpret_cast<float2*>(out + (size_t)i * 2) = r;
}

extern "C" void kernel_launch(void* const* d_in, const int* in_sizes, int n_in,
                              void* d_out, int out_size, void* d_ws, size_t ws_size,
                              hipStream_t stream) {
    const float* g = (const float*)d_in[1];
    float* out = (float*)d_out;
    int* paths = (int*)d_ws;                                        // 3,211,264 B
    unsigned long long* gacc =
        (unsigned long long*)((char*)d_ws + (size_t)BB * 14 * HH * 4);   // 128 KiB

    dp_kernel<<<(BB * 14) / 16, 256, 0, stream>>>(g, paths, gacc);  // 224 blocks
    label_kernel<<<BB * YCH, 256, 0, stream>>>(paths, out, gacc);
    finalize_kernel<<<(BB * KK) / 256, 256, 0, stream>>>(gacc, out);
}